// Round 1
// baseline (43.273 us; speedup 1.0000x reference)
//
#include <hip/hip_runtime.h>
#include <math.h>

#define NH    16384   // Hadamard size (2^14)
#define NRES  8192
#define NINP  64
#define BATCH 512

// Bank-conflict swizzle on float-index: XOR bank bits 2-4 with higher addr bits.
// Verified patterns: LA/LC b128 -> conflict-free; LB b32 -> 2-way (free).
__device__ __forceinline__ int swz(int a) {
    return a ^ (((a >> 5) & 3) << 2) ^ (((a >> 10) & 1) << 4);
}

template <int S>
__device__ __forceinline__ void fwht_stage(float x[64]) {
#pragma unroll
    for (int i = 0; i < 64; ++i) {
        if (!(i & S)) {
            float a = x[i], b = x[i + S];
            x[i]     = a + b;
            x[i + S] = a - b;
        }
    }
}

__device__ __forceinline__ void fwht64(float x[64]) {
    fwht_stage<1>(x);  fwht_stage<2>(x);  fwht_stage<4>(x);
    fwht_stage<8>(x);  fwht_stage<16>(x); fwht_stage<32>(x);
}

// Layouts (idx = position in the 16384-vector), t = threadIdx (8 bits), e = reg (6 bits):
//  LA: idx = (e_hi2<<12) | (t<<4) | e_lo4          owns idx bits {0-3,12,13}
//  LB: idx = ((t>>4)<<10) | (e<<4) | (t&15)        owns idx bits {4-9}
//  LC: idx = ((t>>6)<<12) | (e_hi2<<10) | ((t&63)<<4) | e_lo4   owns {0-3,10,11}

__global__ __launch_bounds__(256, 2) void st_kernel(
    const float* __restrict__ state, const float* __restrict__ inputs,
    const float* __restrict__ bias,  const float* __restrict__ diag,
    float* __restrict__ out)
{
    __shared__ float lds[NH];
    const int t = threadIdx.x;
    const int r = blockIdx.x;

    float x[64];

    // ---------- build X in LA layout ----------
    {
        const float* srow = state + (size_t)r * NRES;
#pragma unroll
        for (int eh = 0; eh < 2; ++eh) {
#pragma unroll
            for (int g = 0; g < 4; ++g) {
                float4 v = *(const float4*)(srow + (eh << 12) + (t << 4) + (g << 2));
                x[eh * 16 + g * 4 + 0] = 0.9f * v.x;
                x[eh * 16 + g * 4 + 1] = 0.9f * v.y;
                x[eh * 16 + g * 4 + 2] = 0.9f * v.z;
                x[eh * 16 + g * 4 + 3] = 0.9f * v.w;
            }
        }
        // idx in [8192, 12288): inputs occupy [8192, 8256) -> threads 0..3
#pragma unroll
        for (int g = 0; g < 4; ++g) {
            float4 v = make_float4(0.f, 0.f, 0.f, 0.f);
            if (t < 4) v = *(const float4*)(inputs + r * NINP + t * 16 + g * 4);
            x[32 + g * 4 + 0] = 0.4f * v.x;
            x[32 + g * 4 + 1] = 0.4f * v.y;
            x[32 + g * 4 + 2] = 0.4f * v.z;
            x[32 + g * 4 + 3] = 0.4f * v.w;
        }
#pragma unroll
        for (int e = 48; e < 64; ++e) x[e] = 0.f;
    }

    // ---------- diag multiply helpers (inline) ----------
    // LA-layout diag multiply
    {
        const float* d0 = diag; // layer 0
#pragma unroll
        for (int eh = 0; eh < 4; ++eh) {
#pragma unroll
            for (int g = 0; g < 4; ++g) {
                float4 d = *(const float4*)(d0 + (eh << 12) + (t << 4) + (g << 2));
                x[eh * 16 + g * 4 + 0] *= d.x;
                x[eh * 16 + g * 4 + 1] *= d.y;
                x[eh * 16 + g * 4 + 2] *= d.z;
                x[eh * 16 + g * 4 + 3] *= d.w;
            }
        }
    }
    fwht64(x);                      // layer1 bits {0-3,12,13}

    // ---------- E1: LA -> LB ----------
    __syncthreads();
#pragma unroll
    for (int eh = 0; eh < 4; ++eh)
#pragma unroll
        for (int g = 0; g < 4; ++g) {
            int a = (eh << 12) | (t << 4) | (g << 2);
            ((float4*)lds)[swz(a) >> 2] = make_float4(
                x[eh * 16 + g * 4 + 0], x[eh * 16 + g * 4 + 1],
                x[eh * 16 + g * 4 + 2], x[eh * 16 + g * 4 + 3]);
        }
    __syncthreads();
#pragma unroll
    for (int e = 0; e < 64; ++e) {
        int a = ((t >> 4) << 10) | (e << 4) | (t & 15);
        x[e] = lds[swz(a)];
    }
    fwht64(x);                      // layer1 bits {4-9}

    // ---------- E2: LB -> LC ----------
    __syncthreads();
#pragma unroll
    for (int e = 0; e < 64; ++e) {
        int a = ((t >> 4) << 10) | (e << 4) | (t & 15);
        lds[swz(a)] = x[e];
    }
    __syncthreads();
    {
        const int baseC = ((t >> 6) << 12) | ((t & 63) << 4);
#pragma unroll
        for (int eh = 0; eh < 4; ++eh)
#pragma unroll
            for (int g = 0; g < 4; ++g) {
                int a = baseC | (eh << 10) | (g << 2);
                float4 v = ((const float4*)lds)[swz(a) >> 2];
                x[eh * 16 + g * 4 + 0] = v.x;
                x[eh * 16 + g * 4 + 1] = v.y;
                x[eh * 16 + g * 4 + 2] = v.z;
                x[eh * 16 + g * 4 + 3] = v.w;
            }
    }
    fwht_stage<16>(x);              // layer1 bit 10
    fwht_stage<32>(x);              // layer1 bit 11 -> layer1 done
    {
        const float* d1 = diag + NH;
        const int baseC = ((t >> 6) << 12) | ((t & 63) << 4);
#pragma unroll
        for (int eh = 0; eh < 4; ++eh) {
#pragma unroll
            for (int g = 0; g < 4; ++g) {
                float4 d = *(const float4*)(d1 + baseC + (eh << 10) + (g << 2));
                x[eh * 16 + g * 4 + 0] *= d.x;
                x[eh * 16 + g * 4 + 1] *= d.y;
                x[eh * 16 + g * 4 + 2] *= d.z;
                x[eh * 16 + g * 4 + 3] *= d.w;
            }
        }
    }
    fwht64(x);                      // layer2 bits {0-3,10,11}

    // ---------- E3: LC -> LB ----------
    __syncthreads();
    {
        const int baseC = ((t >> 6) << 12) | ((t & 63) << 4);
#pragma unroll
        for (int eh = 0; eh < 4; ++eh)
#pragma unroll
            for (int g = 0; g < 4; ++g) {
                int a = baseC | (eh << 10) | (g << 2);
                ((float4*)lds)[swz(a) >> 2] = make_float4(
                    x[eh * 16 + g * 4 + 0], x[eh * 16 + g * 4 + 1],
                    x[eh * 16 + g * 4 + 2], x[eh * 16 + g * 4 + 3]);
            }
    }
    __syncthreads();
#pragma unroll
    for (int e = 0; e < 64; ++e) {
        int a = ((t >> 4) << 10) | (e << 4) | (t & 15);
        x[e] = lds[swz(a)];
    }
    fwht64(x);                      // layer2 bits {4-9}

    // ---------- E4: LB -> LA ----------
    __syncthreads();
#pragma unroll
    for (int e = 0; e < 64; ++e) {
        int a = ((t >> 4) << 10) | (e << 4) | (t & 15);
        lds[swz(a)] = x[e];
    }
    __syncthreads();
#pragma unroll
    for (int eh = 0; eh < 4; ++eh)
#pragma unroll
        for (int g = 0; g < 4; ++g) {
            int a = (eh << 12) | (t << 4) | (g << 2);
            float4 v = ((const float4*)lds)[swz(a) >> 2];
            x[eh * 16 + g * 4 + 0] = v.x;
            x[eh * 16 + g * 4 + 1] = v.y;
            x[eh * 16 + g * 4 + 2] = v.z;
            x[eh * 16 + g * 4 + 3] = v.w;
        }
    fwht_stage<16>(x);              // layer2 bit 12
    fwht_stage<32>(x);              // layer2 bit 13 -> layer2 done
    {
        const float* d2 = diag + 2 * NH;
#pragma unroll
        for (int eh = 0; eh < 4; ++eh) {
#pragma unroll
            for (int g = 0; g < 4; ++g) {
                float4 d = *(const float4*)(d2 + (eh << 12) + (t << 4) + (g << 2));
                x[eh * 16 + g * 4 + 0] *= d.x;
                x[eh * 16 + g * 4 + 1] *= d.y;
                x[eh * 16 + g * 4 + 2] *= d.z;
                x[eh * 16 + g * 4 + 3] *= d.w;
            }
        }
    }
    fwht64(x);                      // layer3 bits {0-3,12,13}

    // ---------- E5: LA -> LB ----------
    __syncthreads();
#pragma unroll
    for (int eh = 0; eh < 4; ++eh)
#pragma unroll
        for (int g = 0; g < 4; ++g) {
            int a = (eh << 12) | (t << 4) | (g << 2);
            ((float4*)lds)[swz(a) >> 2] = make_float4(
                x[eh * 16 + g * 4 + 0], x[eh * 16 + g * 4 + 1],
                x[eh * 16 + g * 4 + 2], x[eh * 16 + g * 4 + 3]);
        }
    __syncthreads();
#pragma unroll
    for (int e = 0; e < 64; ++e) {
        int a = ((t >> 4) << 10) | (e << 4) | (t & 15);
        x[e] = lds[swz(a)];
    }
    fwht64(x);                      // layer3 bits {4-9}

    // ---------- E6: LB -> LC ----------
    __syncthreads();
#pragma unroll
    for (int e = 0; e < 64; ++e) {
        int a = ((t >> 4) << 10) | (e << 4) | (t & 15);
        lds[swz(a)] = x[e];
    }
    __syncthreads();
    {
        const int baseC = ((t >> 6) << 12) | ((t & 63) << 4);
#pragma unroll
        for (int eh = 0; eh < 4; ++eh)
#pragma unroll
            for (int g = 0; g < 4; ++g) {
                int a = baseC | (eh << 10) | (g << 2);
                float4 v = ((const float4*)lds)[swz(a) >> 2];
                x[eh * 16 + g * 4 + 0] = v.x;
                x[eh * 16 + g * 4 + 1] = v.y;
                x[eh * 16 + g * 4 + 2] = v.z;
                x[eh * 16 + g * 4 + 3] = v.w;
            }
    }
    fwht_stage<16>(x);              // layer3 bit 10
    fwht_stage<32>(x);              // layer3 bit 11 -> layer3 done

    // ---------- finalize: z = X[:8192]/NH + bias; out = erf(z) ----------
    // In LC layout idx bit 13 = t bit 7 -> threads 0..127 hold idx < 8192.
    if (t < 128) {
        float* orow = out + (size_t)r * NRES;
        const int baseC = ((t >> 6) << 12) | ((t & 63) << 4); // bit13 = 0 here
        const float inv = 1.0f / (float)NH;
#pragma unroll
        for (int eh = 0; eh < 4; ++eh) {
#pragma unroll
            for (int g = 0; g < 4; ++g) {
                int idx = baseC | (eh << 10) | (g << 2);
                float4 b = *(const float4*)(bias + idx);
                float4 o;
                o.x = erff(x[eh * 16 + g * 4 + 0] * inv + b.x);
                o.y = erff(x[eh * 16 + g * 4 + 1] * inv + b.y);
                o.z = erff(x[eh * 16 + g * 4 + 2] * inv + b.z);
                o.w = erff(x[eh * 16 + g * 4 + 3] * inv + b.w);
                *(float4*)(orow + idx) = o;
            }
        }
    }
}

extern "C" void kernel_launch(void* const* d_in, const int* in_sizes, int n_in,
                              void* d_out, int out_size, void* d_ws, size_t ws_size,
                              hipStream_t stream) {
    (void)in_sizes; (void)n_in; (void)out_size; (void)d_ws; (void)ws_size;
    const float* state  = (const float*)d_in[0];
    const float* inputs = (const float*)d_in[1];
    const float* bias   = (const float*)d_in[2];
    const float* diag   = (const float*)d_in[3];
    float* out = (float*)d_out;

    hipLaunchKernelGGL(st_kernel, dim3(BATCH), dim3(256), 0, stream,
                       state, inputs, bias, diag, out);
}

// Round 2
// 30.971 us; speedup vs baseline: 1.3972x; 1.3972x over previous
//
#include <hip/hip_runtime.h>
#include <math.h>

#define NH    16384   // Hadamard size (2^14)
#define NRES  8192
#define NINP  64
#define BATCH 512

// Physical LDS float-index: p = idx ^ ((idx>>5)&31) ^ ((idx>>10)&31).
// Bijective (only low 5 bits change). For every layout below, a wave's 64
// lanes at fixed reg-index land exactly 2 per bank -> free (m136).
__device__ __forceinline__ constexpr int foldc(int v) {
    return v ^ ((v >> 5) & 31) ^ ((v >> 10) & 31);
}

// Layouts: idx = A_k(t) | B_k(e), fields disjoint; t: 9 bits, e: 5 bits.
// Since fields are disjoint, fold(A|B) = fold(A) ^ fold(B); per-access LDS
// address = Q_k ^ foldc(B_k(e)) with Q_k = foldc(A_k(t)) computed once and
// foldc(B_k(e)) a compile-time constant.
__device__ __forceinline__ constexpr int B1(int e) { return e; }                          // e <-> idx bits 0-4
__device__ __forceinline__ constexpr int B2(int e) { return e << 5; }                     // bits 5-9
__device__ __forceinline__ constexpr int B3(int e) { return ((e >> 1) << 10) | (e & 1); } // e1-4 <-> bits 10-13, e0 <-> bit 0
__device__ __forceinline__ constexpr int B4(int e) { return e << 1; }                     // bits 1-5
__device__ __forceinline__ constexpr int B5(int e) { return e << 6; }                     // bits 6-10
__device__ __forceinline__ constexpr int B6(int e) { return ((e >> 2) << 11) | (e & 3); } // e2-4 <-> bits 11-13, e0-1 <-> bits 0-1
__device__ __forceinline__ constexpr int B7(int e) { return e << 2; }                     // bits 2-6
__device__ __forceinline__ constexpr int B8(int e) { return e << 7; }                     // bits 7-11
__device__ __forceinline__ constexpr int B9(int e) { return ((e >> 3) << 12) | (e & 7); } // e3-4 <-> bits 12-13, e0-2 <-> bits 0-2

#define EXCH_WR(Q, BF) do { _Pragma("unroll") \
    for (int e = 0; e < 32; ++e) lds[(Q) ^ foldc(BF(e))] = x[e]; } while (0)
#define EXCH_RD(Q, BF) do { _Pragma("unroll") \
    for (int e = 0; e < 32; ++e) x[e] = lds[(Q) ^ foldc(BF(e))]; } while (0)

template <int S>
__device__ __forceinline__ void stage32(float x[32]) {
#pragma unroll
    for (int i = 0; i < 32; ++i) {
        if (!(i & S)) {
            float a = x[i], b = x[i | S];
            x[i]     = a + b;
            x[i | S] = a - b;
        }
    }
}
__device__ __forceinline__ void fwht32(float x[32]) {
    stage32<1>(x); stage32<2>(x); stage32<4>(x); stage32<8>(x); stage32<16>(x);
}

__global__ __launch_bounds__(512, 4) void st_kernel(
    const float* __restrict__ state, const float* __restrict__ inputs,
    const float* __restrict__ bias,  const float* __restrict__ diag,
    float* __restrict__ out)
{
    __shared__ float lds[NH];
    const int t = threadIdx.x;   // 0..511
    const int r = blockIdx.x;    // 0..511

    float x[32];

    // Runtime layout bases (t-only) and their folds.
    const int Q1 = foldc(t << 5);
    const int Q2 = foldc(((t >> 5) << 10) | (t & 31));
    const int Q3 = foldc(t << 1);
    const int Q4 = foldc(((t >> 1) << 6) | (t & 1));
    const int Q5 = foldc(((t >> 6) << 11) | (t & 63));
    const int Q6 = foldc(t << 2);
    const int Q7 = foldc(((t >> 2) << 7) | (t & 3));
    const int Q8 = foldc(((t >> 7) << 12) | (t & 127));
    const int Q9 = foldc(t << 3);

    // ---------- P1 load: idx = t*32 + e (thread owns 32 contiguous) ----------
    if (t < 256) {
        const float* srow = state + (size_t)r * NRES + t * 32;
#pragma unroll
        for (int g = 0; g < 8; ++g) {
            float4 v = *(const float4*)(srow + g * 4);
            x[g * 4 + 0] = 0.9f * v.x; x[g * 4 + 1] = 0.9f * v.y;
            x[g * 4 + 2] = 0.9f * v.z; x[g * 4 + 3] = 0.9f * v.w;
        }
    } else if (t < 258) {
        const float* irow = inputs + r * NINP + (t - 256) * 32;
#pragma unroll
        for (int g = 0; g < 8; ++g) {
            float4 v = *(const float4*)(irow + g * 4);
            x[g * 4 + 0] = 0.4f * v.x; x[g * 4 + 1] = 0.4f * v.y;
            x[g * 4 + 2] = 0.4f * v.z; x[g * 4 + 3] = 0.4f * v.w;
        }
    } else {
#pragma unroll
        for (int e = 0; e < 32; ++e) x[e] = 0.f;
    }
    if (t < 258) {   // diag layer 0 (beyond 8256 the values are zero anyway)
        const float* d0 = diag + t * 32;
#pragma unroll
        for (int g = 0; g < 8; ++g) {
            float4 dv = *(const float4*)(d0 + g * 4);
            x[g * 4 + 0] *= dv.x; x[g * 4 + 1] *= dv.y;
            x[g * 4 + 2] *= dv.z; x[g * 4 + 3] *= dv.w;
        }
    }
    fwht32(x);                                   // layer0 bits 0-4

    // ---------- E1: P1 -> P2 ----------
    EXCH_WR(Q1, B1);
    __syncthreads();
    EXCH_RD(Q2, B2);
    fwht32(x);                                   // layer0 bits 5-9

    // ---------- E2: P2 -> P3 ----------
    __syncthreads();
    EXCH_WR(Q2, B2);
    __syncthreads();
    EXCH_RD(Q3, B3);
    stage32<2>(x); stage32<4>(x); stage32<8>(x); stage32<16>(x);  // layer0 bits 10-13
    {   // diag layer 1: idx = (e>>1)*1024 + t*2 + (e&1)
        const float* d1 = diag + NH;
#pragma unroll
        for (int eh = 0; eh < 16; ++eh) {
            float2 dv = *(const float2*)(d1 + eh * 1024 + t * 2);
            x[eh * 2 + 0] *= dv.x;
            x[eh * 2 + 1] *= dv.y;
        }
    }
    stage32<1>(x);                               // layer1 bit 0

    // ---------- E3: P3 -> P4 ----------
    __syncthreads();
    EXCH_WR(Q3, B3);
    __syncthreads();
    EXCH_RD(Q4, B4);
    fwht32(x);                                   // layer1 bits 1-5

    // ---------- E4: P4 -> P5 ----------
    __syncthreads();
    EXCH_WR(Q4, B4);
    __syncthreads();
    EXCH_RD(Q5, B5);
    fwht32(x);                                   // layer1 bits 6-10

    // ---------- E5: P5 -> P6 ----------
    __syncthreads();
    EXCH_WR(Q5, B5);
    __syncthreads();
    EXCH_RD(Q6, B6);
    stage32<4>(x); stage32<8>(x); stage32<16>(x);    // layer1 bits 11-13
    {   // diag layer 2: idx = (e>>2)*2048 + t*4 + (e&3)
        const float* d2 = diag + 2 * NH;
#pragma unroll
        for (int eh = 0; eh < 8; ++eh) {
            float4 dv = *(const float4*)(d2 + eh * 2048 + t * 4);
            x[eh * 4 + 0] *= dv.x; x[eh * 4 + 1] *= dv.y;
            x[eh * 4 + 2] *= dv.z; x[eh * 4 + 3] *= dv.w;
        }
    }
    stage32<1>(x); stage32<2>(x);                // layer2 bits 0-1

    // ---------- E6: P6 -> P7 ----------
    __syncthreads();
    EXCH_WR(Q6, B6);
    __syncthreads();
    EXCH_RD(Q7, B7);
    fwht32(x);                                   // layer2 bits 2-6

    // ---------- E7: P7 -> P8 ----------
    __syncthreads();
    EXCH_WR(Q7, B7);
    __syncthreads();
    EXCH_RD(Q8, B8);
    fwht32(x);                                   // layer2 bits 7-11

    // ---------- E8: P8 -> P9 ----------
    __syncthreads();
    EXCH_WR(Q8, B8);
    __syncthreads();
    EXCH_RD(Q9, B9);
    stage32<8>(x); stage32<16>(x);               // layer2 bits 12-13

    // ---------- epilogue: idx = q*4096 + t*8 + j (q = e>>3, j = e&7) ----------
    {
        float* orow = out + (size_t)r * NRES;
        const float inv = 1.0f / (float)NH;
#pragma unroll
        for (int q = 0; q < 2; ++q) {
            const int base = q * 4096 + t * 8;
#pragma unroll
            for (int h = 0; h < 2; ++h) {
                float4 b = *(const float4*)(bias + base + h * 4);
                float4 o;
                o.x = erff(x[q * 8 + h * 4 + 0] * inv + b.x);
                o.y = erff(x[q * 8 + h * 4 + 1] * inv + b.y);
                o.z = erff(x[q * 8 + h * 4 + 2] * inv + b.z);
                o.w = erff(x[q * 8 + h * 4 + 3] * inv + b.w);
                *(float4*)(orow + base + h * 4) = o;
            }
        }
    }
}

extern "C" void kernel_launch(void* const* d_in, const int* in_sizes, int n_in,
                              void* d_out, int out_size, void* d_ws, size_t ws_size,
                              hipStream_t stream) {
    (void)in_sizes; (void)n_in; (void)out_size; (void)d_ws; (void)ws_size;
    const float* state  = (const float*)d_in[0];
    const float* inputs = (const float*)d_in[1];
    const float* bias   = (const float*)d_in[2];
    const float* diag   = (const float*)d_in[3];
    float* out = (float*)d_out;

    hipLaunchKernelGGL(st_kernel, dim3(BATCH), dim3(512), 0, stream,
                       state, inputs, bias, diag, out);
}